// Round 6
// baseline (507.604 us; speedup 1.0000x reference)
//
#include <hip/hip_runtime.h>
#include <hip/hip_cooperative_groups.h>

namespace cg = cooperative_groups;

// N=64, T=2048, D=256, fp32. out = [context (N*D)] ++ [norm_attention (N*T)].
// softmax+mask+renorm == softmax restricted to t < lens[n]; attn == 0 past lens.
//
// SINGLE cooperative kernel, 512 blocks (2/CU co-resident):
//  P1: compacted chunks (prefix in-block): e = K.q -> LDS (kept across sync),
//      chunk (m,Z) -> ws.   grid.sync()
//  P2: same chunks: row stats from ws (L2-hot) -> final attn written directly;
//      final-scaled ctx partials -> ws.   grid.sync()
//  P3: blocks 0-255 sum partials -> out_ctx; blocks 256-511 zero attn tail.

#define N_B 64
#define T_S 2048
#define D_S 256
#define TPB 256
#define RC 64
#define NC (T_S / RC)  // 32
#define GRID 512
#define MAXC ((NC * N_B + GRID - 1) / GRID)  // 4 chunks/block max

typedef __attribute__((ext_vector_type(4))) float f4;

__device__ __forceinline__ f4 ntload4(const float* p) {
  return __builtin_nontemporal_load((const f4*)p);
}
__device__ __forceinline__ float dot4(f4 a, f4 b, float acc) {
  acc = fmaf(a.x, b.x, acc);
  acc = fmaf(a.y, b.y, acc);
  acc = fmaf(a.z, b.z, acc);
  acc = fmaf(a.w, b.w, acc);
  return acc;
}
__device__ __forceinline__ f4 fma4(float s, f4 a, f4 b) {
  b.x = fmaf(s, a.x, b.x);
  b.y = fmaf(s, a.y, b.y);
  b.z = fmaf(s, a.z, b.z);
  b.w = fmaf(s, a.w, b.w);
  return b;
}

__global__ __launch_bounds__(TPB) void mega_kernel(
    const float* __restrict__ q, const float* __restrict__ k,
    const float* __restrict__ v, const int* __restrict__ lens,
    float2* __restrict__ mzc, float* __restrict__ Oc,
    float* __restrict__ out_ctx, float* __restrict__ out_attn) {
  const int tid = threadIdx.x, lane = tid & 63, wave = tid >> 6;
  const int b = blockIdx.x;

  __shared__ int P[N_B + 1];
  __shared__ float e_all[MAXC][RC];  // energies persist across grid sync
  __shared__ float a_sh[RC];
  __shared__ f4 part[TPB];
  __shared__ float s_mz[2];

  // per-block prefix of ceil(L/64) (compacted chunk list)
  if (wave == 0) {
    int x = (lens[lane] + RC - 1) >> 6;
#pragma unroll
    for (int off = 1; off < 64; off <<= 1) {
      const int y = __shfl_up(x, off, 64);
      if (lane >= off) x += y;
    }
    P[lane + 1] = x;
    if (lane == 0) P[0] = 0;
  }
  __syncthreads();
  const int total = P[N_B];

  // ---------------- phase 1: energies + chunk (m,Z) ----------------
  {
    const int s = lane & 15, qd = lane >> 4;
    int j = 0;
    for (int ci = b; ci < total; ci += GRID, ++j) {
      int lo = 0, hi = N_B;
      while (hi - lo > 1) {
        const int mid = (lo + hi) >> 1;
        if (P[mid] <= ci) lo = mid; else hi = mid;
      }
      const int n = lo, c = ci - P[lo];
      const int L = lens[n];
      const int t0 = c * RC;
      const int tend = min(t0 + RC, L);

      if (tid < RC) e_all[j][tid] = -1e30f;
      __syncthreads();

      const float* qn = q + (size_t)n * D_S + s * 4;
      const f4 q0 = *(const f4*)(qn);
      const f4 q1 = *(const f4*)(qn + 64);
      const f4 q2 = *(const f4*)(qn + 128);
      const f4 q3 = *(const f4*)(qn + 192);
      const float* kb =
          k + ((size_t)n * T_S + t0 + wave * 16 + qd) * D_S + s * 4;
#pragma unroll
      for (int g = 0; g < 4; ++g) {
        const float* krow = kb + (size_t)g * 4 * D_S;  // rows < T_S: in-bounds
        const f4 k0 = ntload4(krow);
        const f4 k1 = ntload4(krow + 64);
        const f4 k2 = ntload4(krow + 128);
        const f4 k3 = ntload4(krow + 192);
        float acc = 0.f;
        acc = dot4(k0, q0, acc);
        acc = dot4(k1, q1, acc);
        acc = dot4(k2, q2, acc);
        acc = dot4(k3, q3, acc);
#pragma unroll
        for (int off = 8; off > 0; off >>= 1) acc += __shfl_xor(acc, off, 64);
        const int r = t0 + wave * 16 + qd + g * 4;
        if (s == 0 && r < tend) e_all[j][r - t0] = acc;
      }
      __syncthreads();
      if (wave == 0) {
        const float e = e_all[j][lane];
        float m = e;
#pragma unroll
        for (int off = 32; off > 0; off >>= 1)
          m = fmaxf(m, __shfl_xor(m, off, 64));
        float z = __expf(e - m);  // e=-1e30 -> 0
#pragma unroll
        for (int off = 32; off > 0; off >>= 1) z += __shfl_xor(z, off, 64);
        if (lane == 0) mzc[n * NC + c] = make_float2(m, z);
      }
    }
  }
  __threadfence();
  cg::this_grid().sync();

  // ------- phase 2: final attn + final-scaled context partials -------
  {
    const int dg = tid & 63, tg = tid >> 6;
    int j = 0;
    for (int ci = b; ci < total; ci += GRID, ++j) {
      int lo = 0, hi = N_B;
      while (hi - lo > 1) {
        const int mid = (lo + hi) >> 1;
        if (P[mid] <= ci) lo = mid; else hi = mid;
      }
      const int n = lo, c = ci - P[lo];
      const int L = lens[n];
      const int t0 = c * RC;
      const int nc = (L + RC - 1) >> 6;

      __syncthreads();  // protect a_sh/s_mz reuse across iterations
      if (wave == 0) {
        float m = -1e30f, z = 0.f;
        if (lane < nc) {
          const float2 mz = mzc[n * NC + lane];
          m = mz.x;
          z = mz.y;
        }
        float M = m;
#pragma unroll
        for (int off = 32; off > 0; off >>= 1)
          M = fmaxf(M, __shfl_xor(M, off, 64));
        float zs = z * __expf(m - M);  // 0 for lanes >= nc
#pragma unroll
        for (int off = 32; off > 0; off >>= 1) zs += __shfl_xor(zs, off, 64);
        if (lane == 0) {
          s_mz[0] = M;
          s_mz[1] = 1.0f / zs;
        }
      }
      __syncthreads();
      if (tid < RC) {
        const float a = __expf(e_all[j][tid] - s_mz[0]) * s_mz[1];
        a_sh[tid] = a;  // 0 for invalid rows
        out_attn[(size_t)n * T_S + t0 + tid] = a;
      }
      __syncthreads();

      const float* vb = v + ((size_t)n * T_S + t0) * D_S + dg * 4;
      f4 a0 = {0.f, 0.f, 0.f, 0.f}, a1 = a0, a2 = a0, a3 = a0;
#pragma unroll
      for (int jj = 0; jj < 4; ++jj) {
        const int r0 = jj * 16 + tg;
        const f4 v0 = ntload4(vb + (size_t)r0 * D_S);
        const f4 v1 = ntload4(vb + (size_t)(r0 + 4) * D_S);
        const f4 v2 = ntload4(vb + (size_t)(r0 + 8) * D_S);
        const f4 v3 = ntload4(vb + (size_t)(r0 + 12) * D_S);
        a0 = fma4(a_sh[r0], v0, a0);
        a1 = fma4(a_sh[r0 + 4], v1, a1);
        a2 = fma4(a_sh[r0 + 8], v2, a2);
        a3 = fma4(a_sh[r0 + 12], v3, a3);
      }
      part[tid] = (a0 + a1) + (a2 + a3);
      __syncthreads();
      if (tg == 0) {
        const f4 r = part[dg] + part[dg + 64] + part[dg + 128] + part[dg + 192];
        ((f4*)(Oc + (size_t)(n * NC + c) * D_S))[dg] = r;  // final-scaled
      }
    }
  }
  __threadfence();
  cg::this_grid().sync();

  // ---------------- phase 3: reduce partials / zero attn tail ----------------
  if (b < 256) {
    const int n = b >> 2, dq = b & 3;
    const int nc = (lens[n] + RC - 1) >> 6;
    const int d = dq * 64 + (tid & 63);
    const int cgi = tid >> 6;
    const float* ob = Oc + (size_t)n * NC * D_S + d;
    float acc = 0.f;
    for (int cc = cgi; cc < nc; cc += 4) acc += ob[(size_t)cc * D_S];
    float* red = (float*)part;
    red[tid] = acc;
    __syncthreads();
    if (tid < 64)
      out_ctx[(size_t)n * D_S + d] =
          (red[tid] + red[tid + 64]) + (red[tid + 128] + red[tid + 192]);
  } else {
    const int b2 = b - 256;
    const int n = b2 >> 2, qr = b2 & 3;
    const int start0 = ((lens[n] + RC - 1) >> 6) << 6;  // nc*64
    const int base = qr * (T_S / 4);
#pragma unroll
    for (int i = 0; i < 2; ++i) {
      const int t = base + i * TPB + tid;
      if (t >= start0) out_attn[(size_t)n * T_S + t] = 0.f;
    }
  }
}

extern "C" void kernel_launch(void* const* d_in, const int* in_sizes, int n_in,
                              void* d_out, int out_size, void* d_ws,
                              size_t ws_size, hipStream_t stream) {
  const float* query = (const float*)d_in[0];
  const float* key = (const float*)d_in[1];
  const float* value = (const float*)d_in[2];
  const int* lens = (const int*)d_in[3];

  float* out_ctx = (float*)d_out;               // N*D
  float* out_attn = (float*)d_out + N_B * D_S;  // N*T

  float2* mzc = (float2*)d_ws;                          // N*NC float2 (16 KB)
  float* Oc = (float*)d_ws + 2 * (size_t)N_B * NC;      // N*NC*D floats (2 MB)

  void* args[8] = {(void*)&query, (void*)&key,   (void*)&value,
                   (void*)&lens,  (void*)&mzc,   (void*)&Oc,
                   (void*)&out_ctx, (void*)&out_attn};
  hipLaunchCooperativeKernel((const void*)mega_kernel, dim3(GRID), dim3(TPB),
                             args, 0, stream);
}

// Round 7
// 245.513 us; speedup vs baseline: 2.0675x; 2.0675x over previous
//
#include <hip/hip_runtime.h>

// N=64, T=2048, D=256, fp32. out = [context (N*D)] ++ [norm_attention (N*T)].
// softmax+mask+renorm == softmax restricted to t < lens[n]; attn == 0 past lens.
// 2 kernels (best structure, R4=241.8us), now with V register-prefetch so the
// V stream is issued before the K-dot/softmax phases (kills the aligned
// memory-idle bubble across co-resident blocks):
//  K1 (n, 64-t chunk): prefetch V->regs; e = K.q (4 rows/wave-pass, 16-lane
//     reduce); chunk (m,Z) + p=exp(e-m) -> ws; O_c = p.V from regs -> ws.
//  K2 (4,n): s_c = exp(m_c-m)/Z; attn = p*s_c (0 past lens); ctx = sum s_c*O_c.

#define N_B 64
#define T_S 2048
#define D_S 256
#define TPB 256
#define RC 64
#define NC (T_S / RC)  // 32

typedef __attribute__((ext_vector_type(4))) float f4;
typedef __attribute__((ext_vector_type(2))) float f2;

__device__ __forceinline__ f4 ntload4(const float* p) {
  return __builtin_nontemporal_load((const f4*)p);
}
__device__ __forceinline__ float dot4(f4 a, f4 b, float acc) {
  acc = fmaf(a.x, b.x, acc);
  acc = fmaf(a.y, b.y, acc);
  acc = fmaf(a.z, b.z, acc);
  acc = fmaf(a.w, b.w, acc);
  return acc;
}
__device__ __forceinline__ f4 fma4(float s, f4 a, f4 b) {
  b.x = fmaf(s, a.x, b.x);
  b.y = fmaf(s, a.y, b.y);
  b.z = fmaf(s, a.z, b.z);
  b.w = fmaf(s, a.w, b.w);
  return b;
}

__global__ __launch_bounds__(TPB, 3) void fused_kernel(
    const float* __restrict__ q, const float* __restrict__ k,
    const float* __restrict__ v, const int* __restrict__ lens,
    float* __restrict__ p_out, float2* __restrict__ mzc,
    float* __restrict__ Oc) {
  const int n = blockIdx.y, c = blockIdx.x;
  const int L = lens[n];
  const int t0 = c * RC;
  if (t0 >= L) return;
  const int tend = min(t0 + RC, L);
  const int tid = threadIdx.x;
  const int lane = tid & 63, wave = tid >> 6;

  __shared__ float e_sh[RC];
  __shared__ float p_sh[RC];
  __shared__ f4 part[TPB];

  // ---- prefetch this chunk's V tile into registers (issued at t=0; the V
  // stream drains while phases 1-2 compute). Rows t0..t0+63 < T_S: in-bounds.
  const int dg = tid & 63, tg = tid >> 6;
  const float* vb = v + ((size_t)n * T_S + t0) * D_S + dg * 4;
  f4 vreg[16];
#pragma unroll
  for (int j = 0; j < 4; ++j) {
    const int r0 = j * 16 + tg;
    vreg[j * 4 + 0] = ntload4(vb + (size_t)r0 * D_S);
    vreg[j * 4 + 1] = ntload4(vb + (size_t)(r0 + 4) * D_S);
    vreg[j * 4 + 2] = ntload4(vb + (size_t)(r0 + 8) * D_S);
    vreg[j * 4 + 3] = ntload4(vb + (size_t)(r0 + 12) * D_S);
  }

  // ---- phase 1: energies. Wave owns 16 rows; 4 rows/pass; lane = (qd -> row,
  // s -> d-quarter). 16 independent K loads/wave; q direct (L2-hot broadcast).
  {
    const int s = lane & 15, qd = lane >> 4;
    const float* qn = q + (size_t)n * D_S + s * 4;
    const f4 q0 = *(const f4*)(qn);
    const f4 q1 = *(const f4*)(qn + 64);
    const f4 q2 = *(const f4*)(qn + 128);
    const f4 q3 = *(const f4*)(qn + 192);
    const float* kb = k + ((size_t)n * T_S + t0 + wave * 16 + qd) * D_S + s * 4;
#pragma unroll
    for (int g = 0; g < 4; ++g) {
      const float* krow = kb + (size_t)g * 4 * D_S;  // rows < T_S: in-bounds
      const f4 k0 = ntload4(krow);
      const f4 k1 = ntload4(krow + 64);
      const f4 k2 = ntload4(krow + 128);
      const f4 k3 = ntload4(krow + 192);
      float acc = 0.f;
      acc = dot4(k0, q0, acc);
      acc = dot4(k1, q1, acc);
      acc = dot4(k2, q2, acc);
      acc = dot4(k3, q3, acc);
#pragma unroll
      for (int off = 8; off > 0; off >>= 1) acc += __shfl_xor(acc, off, 64);
      const int r = t0 + wave * 16 + qd + g * 4;
      if (s == 0) e_sh[r - t0] = (r < tend) ? acc : -1e30f;
    }
  }
  __syncthreads();

  // ---- phase 2: chunk-local softmax partials (invalid rows e=-1e30 -> p=0)
  if (wave == 0) {
    const float e = e_sh[lane];
    float m = e;
#pragma unroll
    for (int off = 32; off > 0; off >>= 1) m = fmaxf(m, __shfl_xor(m, off, 64));
    const float pv = __expf(e - m);
    float z = pv;
#pragma unroll
    for (int off = 32; off > 0; off >>= 1) z += __shfl_xor(z, off, 64);
    p_sh[lane] = pv;
    p_out[(size_t)n * T_S + t0 + lane] = pv;
    if (lane == 0) mzc[n * NC + c] = make_float2(m, z);
  }
  __syncthreads();

  // ---- phase 3: O_c = sum_t p_t * v_t from the prefetched registers.
  f4 a0 = {0.f, 0.f, 0.f, 0.f}, a1 = a0, a2 = a0, a3 = a0;
#pragma unroll
  for (int j = 0; j < 4; ++j) {
    const int r0 = j * 16 + tg;
    a0 = fma4(p_sh[r0], vreg[j * 4 + 0], a0);
    a1 = fma4(p_sh[r0 + 4], vreg[j * 4 + 1], a1);
    a2 = fma4(p_sh[r0 + 8], vreg[j * 4 + 2], a2);
    a3 = fma4(p_sh[r0 + 12], vreg[j * 4 + 3], a3);
  }
  part[tid] = (a0 + a1) + (a2 + a3);
  __syncthreads();
  if (tg == 0) {
    const f4 r = part[dg] + part[dg + 64] + part[dg + 128] + part[dg + 192];
    ((f4*)(Oc + ((size_t)(n * NC + c)) * D_S))[dg] = r;
  }
}

// ---- K2: merge. Block (cx,n): attn t-slice [cx*512, +512), ctx d-slice
// [cx*64, +64). Chunk stats recomputed per block (L2-hot, 16 KB total).
__global__ __launch_bounds__(TPB) void merge_kernel(
    const int* __restrict__ lens, const float* __restrict__ p_in,
    const float2* __restrict__ mzc, const float* __restrict__ Oc,
    float* __restrict__ out_ctx, float* __restrict__ out_attn) {
  const int n = blockIdx.y, cx = blockIdx.x;
  const int L = lens[n];
  const int nc = (L + RC - 1) >> 6;
  const int tid = threadIdx.x;
  __shared__ float s_sh[NC];
  __shared__ float cpart[TPB];

  if (tid < 64) {
    float m = -1e30f, z = 0.f;
    if (tid < nc) {
      const float2 mz = mzc[n * NC + tid];
      m = mz.x;
      z = mz.y;
    }
    float M = m;
#pragma unroll
    for (int off = 32; off > 0; off >>= 1) M = fmaxf(M, __shfl_xor(M, off, 64));
    const float sc = __expf(m - M);  // 0 for invalid chunks
    float zs = z * sc;
#pragma unroll
    for (int off = 32; off > 0; off >>= 1) zs += __shfl_xor(zs, off, 64);
    if (tid < NC) s_sh[tid] = sc / zs;
  }
  __syncthreads();

  // attention slice (float2 per thread; zeros past lens, no read past lens)
  {
    const int t = cx * (T_S / 4) + tid * 2;
    f2 a = {0.f, 0.f};
    if (t < L) {
      const f2 p = *(const f2*)(p_in + (size_t)n * T_S + t);
      const float sc = s_sh[t >> 6];
      a.x = p.x * sc;
      a.y = (t + 1 < L) ? p.y * sc : 0.f;
    }
    *(f2*)(out_attn + (size_t)n * T_S + t) = a;
  }

  // context slice: thread (d = cx*64 + (tid&63), chunk-group tid>>6 of 4);
  // only valid chunks are read.
  {
    const int d = cx * 64 + (tid & 63);
    const int cg = tid >> 6;
    const float* ob = Oc + (size_t)n * NC * D_S + d;
    float acc = 0.f;
    for (int cc = cg; cc < nc; cc += 4)
      acc = fmaf(s_sh[cc], ob[(size_t)cc * D_S], acc);
    cpart[tid] = acc;
    __syncthreads();
    if (tid < 64)
      out_ctx[(size_t)n * D_S + d] =
          (cpart[tid] + cpart[tid + 64]) + (cpart[tid + 128] + cpart[tid + 192]);
  }
}

extern "C" void kernel_launch(void* const* d_in, const int* in_sizes, int n_in,
                              void* d_out, int out_size, void* d_ws,
                              size_t ws_size, hipStream_t stream) {
  const float* query = (const float*)d_in[0];
  const float* key = (const float*)d_in[1];
  const float* value = (const float*)d_in[2];
  const int* lens = (const int*)d_in[3];

  float* out_ctx = (float*)d_out;               // N*D
  float* out_attn = (float*)d_out + N_B * D_S;  // N*T

  float* p = (float*)d_ws;                                 // N*T (512 KB)
  float2* mzc = (float2*)(p + (size_t)N_B * T_S);          // N*NC (16 KB)
  float* Oc = (float*)(mzc + N_B * NC);                    // N*NC*D (2 MB)

  const dim3 grid1(NC, N_B);  // (32, 64)
  fused_kernel<<<grid1, TPB, 0, stream>>>(query, key, value, lens, p, mzc, Oc);
  const dim3 grid2(4, N_B);   // (4, 64)
  merge_kernel<<<grid2, TPB, 0, stream>>>(lens, p, mzc, Oc, out_ctx, out_attn);
}